// Round 2
// baseline (2508.620 us; speedup 1.0000x reference)
//
#include <hip/hip_runtime.h>
#include <stdint.h>

constexpr int kS = 512;   // sequence length
constexpr int kB = 32;    // batch (only element 0 decoded)
constexpr int kH = 512;   // hidden
constexpr int kV = 64;    // tags

// ---------------------------------------------------------------------------
// ws layout (floats):
//   X   [512][512]     @ 0        (262144)
//   H0  [2][512][512]  @ 262144   (524288)   sentinel-initialized
//   H1  [2][512][512]  @ 786432   (524288)   sentinel-initialized
//   LOG [512][64]      @ 1310720  (32768)
// ---------------------------------------------------------------------------

__device__ __forceinline__ float fast_sigmoid(float x) {
  return __builtin_amdgcn_rcpf(1.0f + __expf(-x));
}
__device__ __forceinline__ float fast_tanh(float x) {
  // 1 - 2/(1+e^{2x}): exact at 0, saturates correctly at +-inf
  return 1.0f - 2.0f * __builtin_amdgcn_rcpf(1.0f + __expf(2.0f * x));
}
__device__ __forceinline__ float bcast(float v, int k) {
  return __uint_as_float(__builtin_amdgcn_readlane(__float_as_uint(v), k));
}

__global__ __launch_bounds__(128) void k_embed(const int* __restrict__ src,
                                               const float* __restrict__ emb,
                                               float* __restrict__ X) {
  const int t = blockIdx.x;
  const int s = src[t * kB];  // batch 0 token
  const float4* e = (const float4*)(emb + (size_t)s * 512);
  float4* x = (float4*)(X + (size_t)t * 512);
  x[threadIdx.x] = e[threadIdx.x];
}

// Fused recurrence: grid = 64 blocks (dir = bx&1, wg = bx>>1 of 32), 512 thr.
// wg owns h elements [wg*16, wg*16+16) -> 64 gate rows. Lane l of each wave
// owns gate row l (grow = (l>>4)*512 + wg*16 + (l&15)); wave wv owns k-slice
// [wv*64,+64) of Whh and [wv*(KZ/8),+KZ/8) of Wih. All weights in VGPRs.
// Matvecs use register h/z + readlane broadcast as SGPR FMA operand: zero
// LDS on the critical path. The Wih*z[t] FMAs are recurrence-independent and
// overlap the cross-CU h handoff latency. Handoff: data-is-the-flag, relaxed
// agent atomics, sentinel 0xFFFFFFFF (NaN, unreachable since |h|<1).
template <int KZ>
__global__ __launch_bounds__(512, 2) void k_rec(
    const float* __restrict__ Z0,   // layer0: X; layer1: H0 fwd
    const float* __restrict__ Z1,   // layer1: H0 bwd (unused for KZ==512)
    const float* __restrict__ Wih,  // [2][2048][KZ]
    const float* __restrict__ Whh,  // [2][2048][512]
    const float* __restrict__ bih,  // [2][2048]
    const float* __restrict__ bhh,  // [2][2048]
    float* __restrict__ Hout) {     // [2][512][512], sentinel-initialized
  constexpr int ZPW = KZ / 8;       // z k-slice per wave (64 or 128)
  __shared__ float part[64 * 9];    // [row][wave], stride 9: conflict-free
  __shared__ float gsum[64];
  const int bx = blockIdx.x;
  const int dir = bx & 1, wg = bx >> 1;
  const int tid = threadIdx.x;
  const int wv = tid >> 6, l = tid & 63;
  const float* WihB = Wih + (size_t)dir * 2048 * KZ;
  const float* WhhB = Whh + (size_t)dir * 2048 * 512;
  float* Hb = Hout + (size_t)dir * kS * kH;
  const int grow = (l >> 4) * 512 + wg * 16 + (l & 15);

  // --- one-time weight loads into VGPRs ---
  float ww[64];
  {
    const float* wp = WhhB + (size_t)grow * 512 + wv * 64;
#pragma unroll
    for (int i = 0; i < 64; i += 4) {
      const float4 v = *(const float4*)(wp + i);
      ww[i] = v.x; ww[i + 1] = v.y; ww[i + 2] = v.z; ww[i + 3] = v.w;
    }
  }
  float zw[ZPW];
  {
    const float* zp = WihB + (size_t)grow * KZ + wv * ZPW;
#pragma unroll
    for (int i = 0; i < ZPW; i += 4) {
      const float4 v = *(const float4*)(zp + i);
      zw[i] = v.x; zw[i + 1] = v.y; zw[i + 2] = v.z; zw[i + 3] = v.w;
    }
  }
  float bias = 0.0f;
  if (tid < 64) {
    const int gr = (tid >> 4) * 512 + wg * 16 + (tid & 15);
    bias = bih[dir * 2048 + gr] + bhh[dir * 2048 + gr];
  }
  float cstate = 0.0f;  // live in tid<16 only

  // z-input addressing: per wave a single contiguous 64/128-float slice
  const float* zbase = (KZ == 512) ? Z0 : ((wv < 4) ? Z0 : Z1);
  const int zoff = (KZ == 512) ? tid : ((wv & 3) * 128 + l);

  // prefetch z for first timestep
  int t0 = dir ? (kS - 1) : 0;
  float zc0 = zbase[(size_t)t0 * 512 + zoff];
  float zc1 = (KZ == 1024) ? zbase[(size_t)t0 * 512 + zoff + 64] : 0.0f;

  for (int s = 0; s < kS; s++) {
    const int t = dir ? (kS - 1 - s) : s;
    int tn = dir ? (t - 1) : (t + 1);
    if (tn < 0) tn = 0;
    if (tn > kS - 1) tn = kS - 1;
    // issue next-step z loads early (lands during handoff/compute)
    const float zn0 = zbase[(size_t)tn * 512 + zoff];
    const float zn1 = (KZ == 1024) ? zbase[(size_t)tn * 512 + zoff + 64] : 0.0f;

    // --- input-gate matvec: off the critical path (independent of h) ---
    float acc = 0.0f;
#pragma unroll
    for (int k = 0; k < 64; k++) acc += zw[k] * bcast(zc0, k);
    if (KZ == 1024) {
#pragma unroll
      for (int k = 0; k < 64; k++) acc += zw[64 + k] * bcast(zc1, k);
    }

    // --- poll previous h (own k-slice element) ---
    float hreg = 0.0f;
    if (s > 0) {
      const int tp = dir ? (t + 1) : (t - 1);
      const unsigned* hp = (const unsigned*)(Hb + (size_t)tp * kH) + tid;
      unsigned u;
      do {
        u = __hip_atomic_load(hp, __ATOMIC_RELAXED, __HIP_MEMORY_SCOPE_AGENT);
      } while (u == 0xFFFFFFFFu);
      hreg = __uint_as_float(u);
    }

    // --- recurrent matvec: readlane broadcast, no LDS ---
#pragma unroll
    for (int k = 0; k < 64; k++) acc += ww[k] * bcast(hreg, k);

    part[l * 9 + wv] = acc;
    __syncthreads();
    if (tid < 64) {
      float ssum = bias;
#pragma unroll
      for (int w = 0; w < 8; w++) ssum += part[tid * 9 + w];
      gsum[tid] = ssum;
    }
    __syncthreads();
    if (tid < 16) {
      const float gi = gsum[tid], gf = gsum[16 + tid];
      const float gg = gsum[32 + tid], go = gsum[48 + tid];
      const float ig = fast_sigmoid(gi);
      const float fg = fast_sigmoid(gf);
      const float og = fast_sigmoid(go);
      cstate = fg * cstate + ig * fast_tanh(gg);
      const float h = og * fast_tanh(cstate);
      __hip_atomic_store((unsigned*)(Hb + (size_t)t * kH) + wg * 16 + tid,
                         __float_as_uint(h), __ATOMIC_RELAXED,
                         __HIP_MEMORY_SCOPE_AGENT);
    }
    zc0 = zn0;
    zc1 = zn1;
  }
}

__global__ __launch_bounds__(256) void k_logits(const float* __restrict__ H1,
                                                const float* __restrict__ Wout,
                                                const float* __restrict__ bout,
                                                float* __restrict__ LOG) {
  __shared__ float hl[1024];
  const int t = blockIdx.x;
  const int tid = threadIdx.x;
  float4* hl4 = (float4*)hl;
  if (tid < 128)
    hl4[tid] = ((const float4*)(H1 + (size_t)t * kH))[tid];
  else
    hl4[tid] = ((const float4*)(H1 + (size_t)(kS + t) * kH))[tid - 128];
  __syncthreads();
  const int v = tid >> 2, q = tid & 3;
  const float4* w4 = (const float4*)(Wout + (size_t)v * 1024);
  float4 a = {0, 0, 0, 0};
#pragma unroll 8
  for (int j = 0; j < 64; j++) {
    const int idx = j * 4 + q;
    const float4 w = w4[idx];
    const float4 x = hl4[idx];
    a.x += w.x * x.x; a.y += w.y * x.y; a.z += w.z * x.z; a.w += w.w * x.w;
  }
  float acc = (a.x + a.y) + (a.z + a.w);
  acc += __shfl_xor(acc, 1);
  acc += __shfl_xor(acc, 2);
  if (q == 0) LOG[(size_t)t * kV + v] = acc + bout[v];
}

__global__ __launch_bounds__(256) void k_viterbi(const float* __restrict__ LOG,
                                                 const float* __restrict__ trans,
                                                 int* __restrict__ out) {
  __shared__ float delta[64];
  __shared__ float redS[4 * 64];
  __shared__ int redA[4 * 64];
  __shared__ unsigned char bp[511 * 64];
  const int tid = threadIdx.x;
  const int c = tid & 63, q = tid >> 6;
  if (tid < 64) delta[tid] = LOG[tid];
  __syncthreads();
  for (int t = 1; t < kS; t++) {
    float best = -1e30f;
    int bi = 0;
#pragma unroll 4
    for (int pp = 0; pp < 16; pp++) {
      const int p = q * 16 + pp;
      const float sc = delta[p] + trans[p * 64 + c];
      if (sc > best) { best = sc; bi = p; }  // strict > == first-max (numpy)
    }
    redS[q * 64 + c] = best;
    redA[q * 64 + c] = bi;
    __syncthreads();
    if (tid < 64) {
      float b = redS[c];
      int a = redA[c];
      for (int qq = 1; qq < 4; qq++) {
        const float v2 = redS[qq * 64 + c];
        if (v2 > b) { b = v2; a = redA[qq * 64 + c]; }
      }
      bp[(t - 1) * 64 + c] = (unsigned char)a;
      delta[c] = b + LOG[t * 64 + c];
    }
    __syncthreads();
  }
  if (tid == 0) {
    float b = delta[0];
    int a = 0;
    for (int i = 1; i < 64; i++)
      if (delta[i] > b) { b = delta[i]; a = i; }
    int idx = a;
    out[kS - 1] = idx;
    for (int t = kS - 2; t >= 0; t--) {
      idx = bp[t * 64 + idx];
      out[t] = idx;
    }
  }
}

extern "C" void kernel_launch(void* const* d_in, const int* in_sizes, int n_in,
                              void* d_out, int out_size, void* d_ws,
                              size_t ws_size, hipStream_t stream) {
  (void)in_sizes; (void)n_in; (void)out_size; (void)ws_size;
  const int* source  = (const int*)d_in[0];
  const float* emb   = (const float*)d_in[2];
  const float* Wih0  = (const float*)d_in[3];
  const float* Whh0  = (const float*)d_in[4];
  const float* bih0  = (const float*)d_in[5];
  const float* bhh0  = (const float*)d_in[6];
  const float* Wih1  = (const float*)d_in[7];
  const float* Whh1  = (const float*)d_in[8];
  const float* bih1  = (const float*)d_in[9];
  const float* bhh1  = (const float*)d_in[10];
  const float* Wout  = (const float*)d_in[11];
  const float* bout  = (const float*)d_in[12];
  const float* trans = (const float*)d_in[13];

  float* ws = (float*)d_ws;
  float* X   = ws;
  float* H0  = ws + 262144;
  float* H1  = ws + 786432;
  float* LOG = ws + 1310720;

  // sentinel-init H0|H1: 0xFFFFFFFF == NaN, unreachable for computed h
  hipMemsetAsync(H0, 0xFF, (size_t)1048576 * sizeof(float), stream);

  k_embed<<<kS, 128, 0, stream>>>(source, emb, X);
  k_rec<512><<<64, 512, 0, stream>>>(X, X, Wih0, Whh0, bih0, bhh0, H0);
  k_rec<1024><<<64, 512, 0, stream>>>(H0, H0 + 262144, Wih1, Whh1, bih1, bhh1, H1);
  k_logits<<<kS, 256, 0, stream>>>(H1, Wout, bout, LOG);
  k_viterbi<<<1, 256, 0, stream>>>(LOG, trans, (int*)d_out);
}

// Round 3
// 2111.032 us; speedup vs baseline: 1.1883x; 1.1883x over previous
//
#include <hip/hip_runtime.h>
#include <stdint.h>

constexpr int kS = 512;   // sequence length
constexpr int kB = 32;    // batch (only element 0 decoded)
constexpr int kH = 512;   // hidden
constexpr int kV = 64;    // tags

// ---------------------------------------------------------------------------
// ws layout (floats):
//   X   [512][512]     @ 0        (262144)
//   H0  [2][512][512]  @ 262144   (524288)   sentinel-initialized
//   H1  [2][512][512]  @ 786432   (524288)   sentinel-initialized
//   LOG [512][64]      @ 1310720  (32768)
// ---------------------------------------------------------------------------

__device__ __forceinline__ float fast_sigmoid(float x) {
  return __builtin_amdgcn_rcpf(1.0f + __expf(-x));
}
__device__ __forceinline__ float fast_tanh(float x) {
  // 1 - 2/(1+e^{2x}): exact at 0, saturates correctly at +-inf
  return 1.0f - 2.0f * __builtin_amdgcn_rcpf(1.0f + __expf(2.0f * x));
}
__device__ __forceinline__ float bcast(float v, int k) {
  return __uint_as_float(__builtin_amdgcn_readlane(__float_as_uint(v), k));
}

__global__ __launch_bounds__(128) void k_embed(const int* __restrict__ src,
                                               const float* __restrict__ emb,
                                               float* __restrict__ X) {
  const int t = blockIdx.x;
  const int s = src[t * kB];  // batch 0 token
  const float4* e = (const float4*)(emb + (size_t)s * 512);
  float4* x = (float4*)(X + (size_t)t * 512);
  x[threadIdx.x] = e[threadIdx.x];
}

// Fused recurrence: grid = 64 blocks (dir = bx&1, wg = bx>>1 of 32), 512 thr.
// wg owns h elements [wg*16, wg*16+16) -> 64 gate rows. Lane l of each wave
// owns gate row l; wave wv owns k-slice [wv*64,+64) of Whh and [wv*KZ/8,+KZ/8)
// of Wih. All weights in VGPRs: __launch_bounds__(512,1) -> 2 waves/SIMD ->
// 256-VGPR cap (the (512,2) variant capped at 128 and SPILLED the weights to
// scratch -- round-2 regression, VGPR_Count=112). Matvecs use register h/z +
// readlane broadcast; the Wih*z[t] FMAs are recurrence-independent and hide
// in the cross-CU handoff window. Single barrier per step; gate reduction +
// cell entirely in wave 0 (row sums on lanes 0..63, 3 intra-wave shuffles).
// Handoff: data-is-the-flag, relaxed agent atomics, sentinel 0xFFFFFFFF.
template <int KZ>
__global__ __launch_bounds__(512, 1) void k_rec(
    const float* __restrict__ Z0,   // layer0: X; layer1: H0 fwd
    const float* __restrict__ Z1,   // layer1: H0 bwd (unused for KZ==512)
    const float* __restrict__ Wih,  // [2][2048][KZ]
    const float* __restrict__ Whh,  // [2][2048][512]
    const float* __restrict__ bih,  // [2][2048]
    const float* __restrict__ bhh,  // [2][2048]
    float* __restrict__ Hout) {     // [2][512][512], sentinel-initialized
  constexpr int ZPW = KZ / 8;       // z k-slice per wave (64 or 128)
  __shared__ float part[64 * 9];    // [row][wave], stride 9: conflict-free
  const int bx = blockIdx.x;
  const int dir = bx & 1, wg = bx >> 1;
  const int tid = threadIdx.x;
  const int wv = tid >> 6, l = tid & 63;
  const float* WihB = Wih + (size_t)dir * 2048 * KZ;
  const float* WhhB = Whh + (size_t)dir * 2048 * 512;
  float* Hb = Hout + (size_t)dir * kS * kH;
  const int grow = (l >> 4) * 512 + wg * 16 + (l & 15);

  // --- one-time weight loads into VGPRs ---
  float ww[64];
  {
    const float* wp = WhhB + (size_t)grow * 512 + wv * 64;
#pragma unroll
    for (int i = 0; i < 64; i += 4) {
      const float4 v = *(const float4*)(wp + i);
      ww[i] = v.x; ww[i + 1] = v.y; ww[i + 2] = v.z; ww[i + 3] = v.w;
    }
  }
  float zw[ZPW];
  {
    const float* zp = WihB + (size_t)grow * KZ + wv * ZPW;
#pragma unroll
    for (int i = 0; i < ZPW; i += 4) {
      const float4 v = *(const float4*)(zp + i);
      zw[i] = v.x; zw[i + 1] = v.y; zw[i + 2] = v.z; zw[i + 3] = v.w;
    }
  }
  float bias = 0.0f;
  if (wv == 0) bias = bih[dir * 2048 + grow] + bhh[dir * 2048 + grow];
  float cstate = 0.0f;  // live in wave 0, lanes < 16

  // z-input addressing: per wave a single contiguous 64/128-float slice
  const float* zbase = (KZ == 512) ? Z0 : ((wv < 4) ? Z0 : Z1);
  const int zoff = (KZ == 512) ? tid : ((wv & 3) * 128 + l);

  // prefetch z for first timestep
  const int t0 = dir ? (kS - 1) : 0;
  float zc0 = zbase[(size_t)t0 * 512 + zoff];
  float zc1 = (KZ == 1024) ? zbase[(size_t)t0 * 512 + zoff + 64] : 0.0f;

  for (int s = 0; s < kS; s++) {
    const int t = dir ? (kS - 1 - s) : s;
    int tn = dir ? (t - 1) : (t + 1);
    if (tn < 0) tn = 0;
    if (tn > kS - 1) tn = kS - 1;
    // issue next-step z loads early (lands during matvec/handoff)
    const float zn0 = zbase[(size_t)tn * 512 + zoff];
    const float zn1 = (KZ == 1024) ? zbase[(size_t)tn * 512 + zoff + 64] : 0.0f;

    // --- input-gate matvec: independent of h, hides in handoff window ---
    float a0 = 0.f, a1 = 0.f, a2 = 0.f, a3 = 0.f;
#pragma unroll
    for (int k = 0; k < 64; k += 4) {
      a0 += zw[k + 0] * bcast(zc0, k + 0);
      a1 += zw[k + 1] * bcast(zc0, k + 1);
      a2 += zw[k + 2] * bcast(zc0, k + 2);
      a3 += zw[k + 3] * bcast(zc0, k + 3);
    }
    if (KZ == 1024) {
#pragma unroll
      for (int k = 0; k < 64; k += 4) {
        a0 += zw[64 + k + 0] * bcast(zc1, k + 0);
        a1 += zw[64 + k + 1] * bcast(zc1, k + 1);
        a2 += zw[64 + k + 2] * bcast(zc1, k + 2);
        a3 += zw[64 + k + 3] * bcast(zc1, k + 3);
      }
    }

    // --- poll previous h (own k-slice element) ---
    float hreg = 0.0f;
    if (s > 0) {
      const int tp = dir ? (t + 1) : (t - 1);
      const unsigned* hp = (const unsigned*)(Hb + (size_t)tp * kH) + tid;
      unsigned u;
      do {
        u = __hip_atomic_load(hp, __ATOMIC_RELAXED, __HIP_MEMORY_SCOPE_AGENT);
      } while (u == 0xFFFFFFFFu);
      hreg = __uint_as_float(u);
    }

    // --- recurrent matvec: readlane broadcast, no LDS ---
#pragma unroll
    for (int k = 0; k < 64; k += 4) {
      a0 += ww[k + 0] * bcast(hreg, k + 0);
      a1 += ww[k + 1] * bcast(hreg, k + 1);
      a2 += ww[k + 2] * bcast(hreg, k + 2);
      a3 += ww[k + 3] * bcast(hreg, k + 3);
    }
    part[l * 9 + wv] = (a0 + a1) + (a2 + a3);
    __syncthreads();
    // waves 1..7 fall through to the next step's z-matvec immediately;
    // reduction + cell + publish is wave 0 only.
    if (wv == 0) {
      float ssum = bias;
#pragma unroll
      for (int w = 0; w < 8; w++) ssum += part[l * 9 + w];
      // lanes: rows i=[0,16) f=[16,32) g=[32,48) o=[48,64)
      const float sf = __shfl(ssum, (l + 16) & 63);
      const float sg = __shfl(ssum, (l + 32) & 63);
      const float so = __shfl(ssum, (l + 48) & 63);
      if (l < 16) {
        const float ig = fast_sigmoid(ssum);
        const float fg = fast_sigmoid(sf);
        const float og = fast_sigmoid(so);
        cstate = fg * cstate + ig * fast_tanh(sg);
        const float h = og * fast_tanh(cstate);
        __hip_atomic_store((unsigned*)(Hb + (size_t)t * kH) + wg * 16 + l,
                           __float_as_uint(h), __ATOMIC_RELAXED,
                           __HIP_MEMORY_SCOPE_AGENT);
      }
    }
    zc0 = zn0;
    zc1 = zn1;
  }
}

__global__ __launch_bounds__(256) void k_logits(const float* __restrict__ H1,
                                                const float* __restrict__ Wout,
                                                const float* __restrict__ bout,
                                                float* __restrict__ LOG) {
  __shared__ float hl[1024];
  const int t = blockIdx.x;
  const int tid = threadIdx.x;
  float4* hl4 = (float4*)hl;
  if (tid < 128)
    hl4[tid] = ((const float4*)(H1 + (size_t)t * kH))[tid];
  else
    hl4[tid] = ((const float4*)(H1 + (size_t)(kS + t) * kH))[tid - 128];
  __syncthreads();
  const int v = tid >> 2, q = tid & 3;
  const float4* w4 = (const float4*)(Wout + (size_t)v * 1024);
  float4 a = {0, 0, 0, 0};
#pragma unroll 8
  for (int j = 0; j < 64; j++) {
    const int idx = j * 4 + q;
    const float4 w = w4[idx];
    const float4 x = hl4[idx];
    a.x += w.x * x.x; a.y += w.y * x.y; a.z += w.z * x.z; a.w += w.w * x.w;
  }
  float acc = (a.x + a.y) + (a.z + a.w);
  acc += __shfl_xor(acc, 1);
  acc += __shfl_xor(acc, 2);
  if (q == 0) LOG[(size_t)t * kV + v] = acc + bout[v];
}

__global__ __launch_bounds__(256) void k_viterbi(const float* __restrict__ LOG,
                                                 const float* __restrict__ trans,
                                                 int* __restrict__ out) {
  __shared__ float delta[64];
  __shared__ float redS[4 * 64];
  __shared__ int redA[4 * 64];
  __shared__ unsigned char bp[511 * 64];
  const int tid = threadIdx.x;
  const int c = tid & 63, q = tid >> 6;
  if (tid < 64) delta[tid] = LOG[tid];
  __syncthreads();
  for (int t = 1; t < kS; t++) {
    float best = -1e30f;
    int bi = 0;
#pragma unroll 4
    for (int pp = 0; pp < 16; pp++) {
      const int p = q * 16 + pp;
      const float sc = delta[p] + trans[p * 64 + c];
      if (sc > best) { best = sc; bi = p; }  // strict > == first-max (numpy)
    }
    redS[q * 64 + c] = best;
    redA[q * 64 + c] = bi;
    __syncthreads();
    if (tid < 64) {
      float b = redS[c];
      int a = redA[c];
      for (int qq = 1; qq < 4; qq++) {
        const float v2 = redS[qq * 64 + c];
        if (v2 > b) { b = v2; a = redA[qq * 64 + c]; }
      }
      bp[(t - 1) * 64 + c] = (unsigned char)a;
      delta[c] = b + LOG[t * 64 + c];
    }
    __syncthreads();
  }
  if (tid == 0) {
    float b = delta[0];
    int a = 0;
    for (int i = 1; i < 64; i++)
      if (delta[i] > b) { b = delta[i]; a = i; }
    int idx = a;
    out[kS - 1] = idx;
    for (int t = kS - 2; t >= 0; t--) {
      idx = bp[t * 64 + idx];
      out[t] = idx;
    }
  }
}

extern "C" void kernel_launch(void* const* d_in, const int* in_sizes, int n_in,
                              void* d_out, int out_size, void* d_ws,
                              size_t ws_size, hipStream_t stream) {
  (void)in_sizes; (void)n_in; (void)out_size; (void)ws_size;
  const int* source  = (const int*)d_in[0];
  const float* emb   = (const float*)d_in[2];
  const float* Wih0  = (const float*)d_in[3];
  const float* Whh0  = (const float*)d_in[4];
  const float* bih0  = (const float*)d_in[5];
  const float* bhh0  = (const float*)d_in[6];
  const float* Wih1  = (const float*)d_in[7];
  const float* Whh1  = (const float*)d_in[8];
  const float* bih1  = (const float*)d_in[9];
  const float* bhh1  = (const float*)d_in[10];
  const float* Wout  = (const float*)d_in[11];
  const float* bout  = (const float*)d_in[12];
  const float* trans = (const float*)d_in[13];

  float* ws = (float*)d_ws;
  float* X   = ws;
  float* H0  = ws + 262144;
  float* H1  = ws + 786432;
  float* LOG = ws + 1310720;

  // sentinel-init H0|H1: 0xFFFFFFFF == NaN, unreachable for computed h.
  // Must run every launch: harness re-poisons ws with 0xAA (a small valid
  // float) which would otherwise defeat the data-is-the-flag protocol.
  hipMemsetAsync(H0, 0xFF, (size_t)1048576 * sizeof(float), stream);

  k_embed<<<kS, 128, 0, stream>>>(source, emb, X);
  k_rec<512><<<64, 512, 0, stream>>>(X, X, Wih0, Whh0, bih0, bhh0, H0);
  k_rec<1024><<<64, 512, 0, stream>>>(H0, H0 + 262144, Wih1, Whh1, bih1, bhh1, H1);
  k_logits<<<kS, 256, 0, stream>>>(H1, Wout, bout, LOG);
  k_viterbi<<<1, 256, 0, stream>>>(LOG, trans, (int*)d_out);
}